// Round 2
// baseline (614.382 us; speedup 1.0000x reference)
//
#include <hip/hip_runtime.h>
#include <hip/hip_bf16.h>
#include <stdint.h>

typedef __attribute__((ext_vector_type(4))) float f32x4;
typedef __attribute__((ext_vector_type(8))) short short8;

#define B_   64
#define S_   512
#define H_   1024
#define E_   512
#define V_   32000
#define M_   2048            // D*H
#define BS_  32768           // B*S
#define XIN_ 2560            // M_+E_
#define G3_  3072

__device__ __forceinline__ unsigned short f2bf(float f) {
  union { float f; unsigned u; } x; x.f = f;
  unsigned r = x.u + 0x7fffu + ((x.u >> 16) & 1u);
  return (unsigned short)(r >> 16);
}

__device__ __forceinline__ void async16(const void* g, void* l) {
  __builtin_amdgcn_global_load_lds((const __attribute__((address_space(1))) unsigned*)g,
                                   (__attribute__((address_space(3))) unsigned*)l,
                                   16, 0, 0);
}

// ---------------- enc f32 -> bf16 (one-time, pure BW) ----------------
__global__ __launch_bounds__(256) void k_enc2bf(const float* __restrict__ enc,
                                                unsigned short* __restrict__ ebf) {
  const size_t n4 = (size_t)BS_ * M_ / 4;  // 16,777,216
  for (size_t i = (size_t)blockIdx.x * 256 + threadIdx.x; i < n4;
       i += (size_t)gridDim.x * 256) {
    f32x4 v = *(const f32x4*)(enc + i * 4);
    ushort4 o = { f2bf(v.x), f2bf(v.y), f2bf(v.z), f2bf(v.w) };
    *(ushort4*)(ebf + i * 4) = o;
  }
}

// ---------------- prep: lin2_w -> bf16, word embedding gather ----------------
__global__ __launch_bounds__(256) void k_prep(const float* __restrict__ lin2w,
                                              unsigned short* __restrict__ bw,
                                              const int* __restrict__ word,
                                              const float* __restrict__ emb,
                                              float* __restrict__ wv) {
  int idx = blockIdx.x * 256 + threadIdx.x;
  const int NC = (H_ * M_) / 4;  // 524288
  if (idx < NC) {
    f32x4 v = *(const f32x4*)(lin2w + (size_t)idx * 4);
    ushort4 o = { f2bf(v.x), f2bf(v.y), f2bf(v.z), f2bf(v.w) };
    *(ushort4*)(bw + (size_t)idx * 4) = o;
  } else {
    int i2 = idx - NC;
    if (i2 < (B_ * E_) / 4) {    // 8192
      int i0 = i2 * 4;
      int b = i0 >> 9;
      int c = i0 & 511;
      f32x4 v = *(const f32x4*)(emb + (size_t)word[b] * E_ + c);
      *(f32x4*)(wv + i0) = v;
    }
  }
}

// ---------------- h_x = hidden @ lin1_w.T + b1 + b2 (LDS-tiled 64x64) -------
__global__ __launch_bounds__(256) void k_hx(const float* __restrict__ hidden,
                                            const float* __restrict__ w1,
                                            const float* __restrict__ b1,
                                            const float* __restrict__ b2,
                                            float* __restrict__ hx) {
  __shared__ float hs[64][36];
  __shared__ float Ws[64][36];
  const int t = threadIdx.x;
  const int hbase = blockIdx.x * 64;     // 16 blocks
  const int hb = t & 15, bb = t >> 4;
  const int srow = t >> 2, sc0 = (t & 3) * 8;
  float acc[4][4] = {};
  for (int kc = 0; kc < H_; kc += 32) {
    *(f32x4*)&hs[srow][sc0]     = *(const f32x4*)(hidden + (size_t)srow * H_ + kc + sc0);
    *(f32x4*)&hs[srow][sc0 + 4] = *(const f32x4*)(hidden + (size_t)srow * H_ + kc + sc0 + 4);
    *(f32x4*)&Ws[srow][sc0]     = *(const f32x4*)(w1 + (size_t)(hbase + srow) * H_ + kc + sc0);
    *(f32x4*)&Ws[srow][sc0 + 4] = *(const f32x4*)(w1 + (size_t)(hbase + srow) * H_ + kc + sc0 + 4);
    __syncthreads();
#pragma unroll
    for (int kk = 0; kk < 32; ++kk) {
      float a[4], w4[4];
#pragma unroll
      for (int i = 0; i < 4; ++i) a[i] = hs[bb * 4 + i][kk];
#pragma unroll
      for (int j = 0; j < 4; ++j) w4[j] = Ws[hb + 16 * j][kk];
#pragma unroll
      for (int i = 0; i < 4; ++i)
#pragma unroll
        for (int j = 0; j < 4; ++j) acc[i][j] += a[i] * w4[j];
    }
    __syncthreads();
  }
#pragma unroll
  for (int i = 0; i < 4; ++i)
#pragma unroll
    for (int j = 0; j < 4; ++j) {
      int h = hbase + hb + 16 * j;
      hx[(size_t)(bb * 4 + i) * H_ + h] = acc[i][j] + b1[h] + b2[h];
    }
}

// ---------------- attention GEMM (fast path): both operands bf16 ------------
// A = encbf [32768 x 2048], B^T = lin2w_bf16 [1024 x 2048]
// m97 structure: tile 128x128, BK=32, global_load_lds x4, 16 MFMA / K-step
__global__ __launch_bounds__(256) void k_attn_bf(const unsigned short* __restrict__ encbf,
                                                 const unsigned short* __restrict__ bw,
                                                 const float* __restrict__ hx,
                                                 const float* __restrict__ vw,
                                                 float* __restrict__ epart) {
  __shared__ unsigned short As[128 * 32];
  __shared__ unsigned short Bs[128 * 32];
  const int bid = blockIdx.x;
  const int bm = bid & 255, bn = bid >> 8;   // same-bm blocks share bid%8 -> same XCD
  const int t = threadIdx.x;
  const int l = t & 63, w = t >> 6;
  const int wr = w >> 1, wc = w & 1;
  const int l15 = l & 15, l4 = l >> 4;

  f32x4 acc[4][4] = {};

  const unsigned short* Ag = encbf + (size_t)(bm * 128) * M_;
  const unsigned short* Bg = bw + (size_t)(bn * 128) * M_;

  const int sr = t >> 2;           // stage row (+64 for 2nd half)
  const int sc = (t & 3) * 8;      // stage col (bf16 elems)

  for (int kt = 0; kt < 64; ++kt) {
    const int k0 = kt * 32;
    async16(Ag + (size_t)sr * M_ + k0 + sc, (char*)As + (size_t)t * 16);
    async16(Ag + (size_t)(sr + 64) * M_ + k0 + sc, (char*)As + 4096 + (size_t)t * 16);
    async16(Bg + (size_t)sr * M_ + k0 + sc, (char*)Bs + (size_t)t * 16);
    async16(Bg + (size_t)(sr + 64) * M_ + k0 + sc, (char*)Bs + 4096 + (size_t)t * 16);
    __syncthreads();
    short8 af[4], bf[4];
#pragma unroll
    for (int m = 0; m < 4; ++m)
      af[m] = *(const short8*)(As + (wr * 64 + m * 16 + l15) * 32 + l4 * 8);
#pragma unroll
    for (int n = 0; n < 4; ++n)
      bf[n] = *(const short8*)(Bs + (wc * 64 + n * 16 + l15) * 32 + l4 * 8);
#pragma unroll
    for (int m = 0; m < 4; ++m)
#pragma unroll
      for (int n = 0; n < 4; ++n)
        acc[m][n] = __builtin_amdgcn_mfma_f32_16x16x32_bf16(af[m], bf[n], acc[m][n], 0, 0, 0);
    __syncthreads();
  }

  const int colbase = bn * 128 + wc * 64;
#pragma unroll
  for (int m = 0; m < 4; ++m) {
#pragma unroll
    for (int j = 0; j < 4; ++j) {
      int rloc = wr * 64 + m * 16 + l4 * 4 + j;
      int rg = bm * 128 + rloc;
      int b = rg >> 9;
      float sum = 0.f;
#pragma unroll
      for (int n = 0; n < 4; ++n) {
        int h = colbase + n * 16 + l15;
        sum += vw[h] * tanhf(hx[b * H_ + h] + acc[m][n][j]);
      }
      sum += __shfl_xor(sum, 1);
      sum += __shfl_xor(sum, 2);
      sum += __shfl_xor(sum, 4);
      sum += __shfl_xor(sum, 8);
      if (l15 == 0) epart[(size_t)(bn * 2 + wc) * BS_ + rg] = sum;
    }
  }
}

// ---------------- attention GEMM (fallback: fused f32 A conversion) ---------
__global__ __launch_bounds__(256) void k_attn(const float* __restrict__ enc,
                                              const unsigned short* __restrict__ bw,
                                              const float* __restrict__ hx,
                                              const float* __restrict__ vw,
                                              float* __restrict__ epart) {
  __shared__ unsigned short As[128 * 32];
  __shared__ unsigned short Bs[128 * 32];
  const int bid = blockIdx.x;
  const int bm = bid & 255, bn = bid >> 8;
  const int t = threadIdx.x;
  const int l = t & 63, w = t >> 6;
  const int wr = w >> 1, wc = w & 1;
  const int l15 = l & 15, l4 = l >> 4;

  f32x4 acc[4][4] = {};

  const float* Ag = enc + (size_t)(bm * 128) * M_;
  const unsigned short* Bg = bw + (size_t)(bn * 128) * M_;

  const int ar = t >> 3;
  const int ac = (t & 7) * 4;
  const int br = t >> 2;
  const int bc = (t & 3) * 8;

  for (int kt = 0; kt < 64; ++kt) {
    const int k0 = kt * 32;
    async16(Bg + (size_t)br * M_ + k0 + bc, (char*)Bs + (size_t)t * 16);
    async16(Bg + (size_t)(br + 64) * M_ + k0 + bc, (char*)Bs + 4096 + (size_t)t * 16);
#pragma unroll
    for (int j = 0; j < 4; ++j) {
      f32x4 v = *(const f32x4*)(Ag + (size_t)(ar + j * 32) * M_ + k0 + ac);
      ushort4 o = { f2bf(v.x), f2bf(v.y), f2bf(v.z), f2bf(v.w) };
      *(ushort4*)(As + (ar + j * 32) * 32 + ac) = o;
    }
    __syncthreads();
    short8 af[4], bf[4];
#pragma unroll
    for (int m = 0; m < 4; ++m)
      af[m] = *(const short8*)(As + (wr * 64 + m * 16 + l15) * 32 + l4 * 8);
#pragma unroll
    for (int n = 0; n < 4; ++n)
      bf[n] = *(const short8*)(Bs + (wc * 64 + n * 16 + l15) * 32 + l4 * 8);
#pragma unroll
    for (int m = 0; m < 4; ++m)
#pragma unroll
      for (int n = 0; n < 4; ++n)
        acc[m][n] = __builtin_amdgcn_mfma_f32_16x16x32_bf16(af[m], bf[n], acc[m][n], 0, 0, 0);
    __syncthreads();
  }

  const int colbase = bn * 128 + wc * 64;
#pragma unroll
  for (int m = 0; m < 4; ++m) {
#pragma unroll
    for (int j = 0; j < 4; ++j) {
      int rloc = wr * 64 + m * 16 + l4 * 4 + j;
      int rg = bm * 128 + rloc;
      int b = rg >> 9;
      float sum = 0.f;
#pragma unroll
      for (int n = 0; n < 4; ++n) {
        int h = colbase + n * 16 + l15;
        sum += vw[h] * tanhf(hx[b * H_ + h] + acc[m][n][j]);
      }
      sum += __shfl_xor(sum, 1);
      sum += __shfl_xor(sum, 2);
      sum += __shfl_xor(sum, 4);
      sum += __shfl_xor(sum, 8);
      if (l15 == 0) epart[(size_t)(bn * 2 + wc) * BS_ + rg] = sum;
    }
  }
}

// ---------------- softmax over S per batch row (reduces 16 e-partials) ------
__global__ __launch_bounds__(256) void k_softmax(const float* __restrict__ epart,
                                                 float* __restrict__ score) {
  int b = blockIdx.x, t = threadIdx.x;
  float v0 = 0.f, v1 = 0.f;
#pragma unroll
  for (int p = 0; p < 16; ++p) {
    v0 += epart[(size_t)p * BS_ + b * S_ + t];
    v1 += epart[(size_t)p * BS_ + b * S_ + 256 + t];
  }
  int w = t >> 6, l = t & 63;
  float m = fmaxf(v0, v1);
#pragma unroll
  for (int off = 32; off; off >>= 1) m = fmaxf(m, __shfl_xor(m, off));
  __shared__ float sm[4];
  __shared__ float ssum[4];
  if (l == 0) sm[w] = m;
  __syncthreads();
  float M = fmaxf(fmaxf(sm[0], sm[1]), fmaxf(sm[2], sm[3]));
  float p0 = expf(v0 - M), p1 = expf(v1 - M);
  float s = p0 + p1;
#pragma unroll
  for (int off = 32; off; off >>= 1) s += __shfl_xor(s, off);
  if (l == 0) ssum[w] = s;
  __syncthreads();
  float inv = 1.f / (ssum[0] + ssum[1] + ssum[2] + ssum[3]);
  score[b * S_ + t] = p0 * inv;
  score[b * S_ + 256 + t] = p1 * inv;
}

// ---------------- context partials ----------------
__global__ __launch_bounds__(256) void k_ctx(const float* __restrict__ enc,
                                             const float* __restrict__ score,
                                             float* __restrict__ cpart) {
  int blk = blockIdx.x;
  int b = blk >> 4, mc = (blk >> 3) & 1, sc = blk & 7;
  int t = threadIdx.x;
  int m = mc * 1024 + t * 4;
  f32x4 acc = {0.f, 0.f, 0.f, 0.f};
  const float* ep = enc + (size_t)b * S_ * M_ + m;
  const float* sp = score + b * S_ + sc * 64;
#pragma unroll 4
  for (int s8 = 0; s8 < 64; ++s8) {
    float sv = sp[s8];
    f32x4 v = *(const f32x4*)(ep + (size_t)(sc * 64 + s8) * M_);
    acc += v * sv;
  }
  *(f32x4*)(cpart + (size_t)sc * (B_ * M_) + b * M_ + m) = acc;
}

__global__ void k_ctxred(const float* __restrict__ cpart, float* __restrict__ ctx) {
  int i0 = (blockIdx.x * 256 + threadIdx.x) * 4;
  f32x4 a = {0.f, 0.f, 0.f, 0.f};
#pragma unroll
  for (int p = 0; p < 8; ++p) a += *(const f32x4*)(cpart + (size_t)p * (B_ * M_) + i0);
  *(f32x4*)(ctx + i0) = a;
}

// ---------------- GRU input/hidden GEMMs ----------------
__global__ __launch_bounds__(256) void k_grugemm(const float* __restrict__ ctx,
                                                 const float* __restrict__ wv,
                                                 const float* __restrict__ hidden,
                                                 const float* __restrict__ Wih,
                                                 const float* __restrict__ bih,
                                                 const float* __restrict__ Whh,
                                                 const float* __restrict__ bhh,
                                                 float* __restrict__ gi,
                                                 float* __restrict__ gh) {
  __shared__ float xs[64][36];
  __shared__ float Ws[16][36];
  const int t = threadIdx.x;
  const bool ghh = blockIdx.x >= 192;
  const int gbase = (ghh ? blockIdx.x - 192 : blockIdx.x) * 16;
  const int K = ghh ? H_ : XIN_;
  const float* Wp = ghh ? Whh : Wih;
  float acc[4] = {0.f, 0.f, 0.f, 0.f};
  const int g = t & 15, bb = t >> 4;
  const int srow = t >> 2, sc0 = (t & 3) * 8;
  const int wrow = t >> 3, wc0 = (t & 7) * 4;
  for (int kc = 0; kc < K; kc += 32) {
    f32x4 xa, xb;
    if (ghh) {
      xa = *(const f32x4*)(hidden + (size_t)srow * H_ + kc + sc0);
      xb = *(const f32x4*)(hidden + (size_t)srow * H_ + kc + sc0 + 4);
    } else if (kc + sc0 < M_) {
      xa = *(const f32x4*)(ctx + (size_t)srow * M_ + kc + sc0);
      xb = *(const f32x4*)(ctx + (size_t)srow * M_ + kc + sc0 + 4);
    } else {
      xa = *(const f32x4*)(wv + (size_t)srow * E_ + kc + sc0 - M_);
      xb = *(const f32x4*)(wv + (size_t)srow * E_ + kc + sc0 - M_ + 4);
    }
    *(f32x4*)&xs[srow][sc0] = xa;
    *(f32x4*)&xs[srow][sc0 + 4] = xb;
    if (t < 128) {
      f32x4 w4 = *(const f32x4*)(Wp + (size_t)(gbase + wrow) * K + kc + wc0);
      *(f32x4*)&Ws[wrow][wc0] = w4;
    }
    __syncthreads();
#pragma unroll
    for (int kk = 0; kk < 32; ++kk) {
      float wgt = Ws[g][kk];
#pragma unroll
      for (int i = 0; i < 4; ++i) acc[i] += xs[bb * 4 + i][kk] * wgt;
    }
    __syncthreads();
  }
  float* dst = ghh ? gh : gi;
  const float* bias = ghh ? bhh : bih;
#pragma unroll
  for (int i = 0; i < 4; ++i)
    dst[(size_t)(bb * 4 + i) * G3_ + gbase + g] = acc[i] + bias[gbase + g];
}

// ---------------- GRU gates -> new_hidden ----------------
__global__ void k_gate(const float* __restrict__ gi, const float* __restrict__ gh,
                       const float* __restrict__ hidden, float* __restrict__ newh) {
  int o = blockIdx.x * 256 + threadIdx.x;
  int b = o >> 10, h = o & 1023;
  const float* gib = gi + (size_t)b * G3_;
  const float* ghb = gh + (size_t)b * G3_;
  float r = 1.f / (1.f + expf(-(gib[h] + ghb[h])));
  float z = 1.f / (1.f + expf(-(gib[1024 + h] + ghb[1024 + h])));
  float n = tanhf(gib[2048 + h] + r * ghb[2048 + h]);
  newh[o] = (1.f - z) * n + z * hidden[o];
}

// ---------------- output projection ----------------
__global__ __launch_bounds__(256) void k_outproj(const float* __restrict__ newh,
                                                 const float* __restrict__ ow,
                                                 const float* __restrict__ ob,
                                                 float* __restrict__ pred) {
  __shared__ float hs[64][36];
  __shared__ float Ws[64][36];
  const int t = threadIdx.x;
  const int vbase = blockIdx.x * 64;
  const int vb = t & 15, bb = t >> 4;
  const int srow = t >> 2, sc0 = (t & 3) * 8;
  float acc[4][4] = {};
  for (int kc = 0; kc < H_; kc += 32) {
    *(f32x4*)&hs[srow][sc0]     = *(const f32x4*)(newh + (size_t)srow * H_ + kc + sc0);
    *(f32x4*)&hs[srow][sc0 + 4] = *(const f32x4*)(newh + (size_t)srow * H_ + kc + sc0 + 4);
    *(f32x4*)&Ws[srow][sc0]     = *(const f32x4*)(ow + (size_t)(vbase + srow) * H_ + kc + sc0);
    *(f32x4*)&Ws[srow][sc0 + 4] = *(const f32x4*)(ow + (size_t)(vbase + srow) * H_ + kc + sc0 + 4);
    __syncthreads();
#pragma unroll
    for (int kk = 0; kk < 32; ++kk) {
      float a[4], w4[4];
#pragma unroll
      for (int i = 0; i < 4; ++i) a[i] = hs[bb * 4 + i][kk];
#pragma unroll
      for (int j = 0; j < 4; ++j) w4[j] = Ws[vb + 16 * j][kk];
#pragma unroll
      for (int i = 0; i < 4; ++i)
#pragma unroll
        for (int j = 0; j < 4; ++j) acc[i][j] += a[i] * w4[j];
    }
    __syncthreads();
  }
#pragma unroll
  for (int i = 0; i < 4; ++i)
#pragma unroll
    for (int j = 0; j < 4; ++j)
      pred[(size_t)(bb * 4 + i) * V_ + vbase + vb + 16 * j] = acc[i][j] + ob[vbase + vb + 16 * j];
}

extern "C" void kernel_launch(void* const* d_in, const int* in_sizes, int n_in,
                              void* d_out, int out_size, void* d_ws, size_t ws_size,
                              hipStream_t stream) {
  const int*   word   = (const int*)d_in[0];
  const float* hidden = (const float*)d_in[1];
  const float* enc    = (const float*)d_in[2];
  const float* emb    = (const float*)d_in[5];
  const float* lin1w  = (const float*)d_in[6];
  const float* lin1b  = (const float*)d_in[7];
  const float* lin2w  = (const float*)d_in[8];
  const float* lin2b  = (const float*)d_in[9];
  const float* vw     = (const float*)d_in[10];
  const float* Wih    = (const float*)d_in[12];
  const float* bih    = (const float*)d_in[13];
  const float* Whh    = (const float*)d_in[14];
  const float* bhh    = (const float*)d_in[15];
  const float* ow     = (const float*)d_in[16];
  const float* ob     = (const float*)d_in[17];

  float* out   = (float*)d_out;
  float* pred  = out;                   // [64][32000]
  float* newh  = out + 2048000;         // [64][1024]
  float* score = out + 2113536;         // [64][512]

  const size_t ENCBF = 134217728;       // 32768*2048*2
  const bool fast = ws_size >= ENCBF + 12976128;
  char* ws = (char*)d_ws;
  unsigned short* encbf = (unsigned short*)ws;      // fast path only
  size_t base = fast ? ENCBF : 0;
  unsigned short* bw = (unsigned short*)(ws + base);        // 4,194,304
  float* hx    = (float*)(ws + base + 4194304);             // 262,144
  float* wvbuf = (float*)(ws + base + 4456448);             // 131,072
  float* epart = (float*)(ws + base + 4587520);             // 2,097,152
  float* cpart = (float*)(ws + base + 6684672);             // 4,194,304
  float* ctx   = (float*)(ws + base + 10878976);            // 524,288
  float* gi    = (float*)(ws + base + 11403264);            // 786,432
  float* gh    = (float*)(ws + base + 12189696);            // 786,432

  k_prep<<<2080, 256, 0, stream>>>(lin2w, bw, word, emb, wvbuf);
  k_hx<<<16, 256, 0, stream>>>(hidden, lin1w, lin1b, lin2b, hx);
  if (fast) {
    k_enc2bf<<<2048, 256, 0, stream>>>(enc, encbf);
    k_attn_bf<<<2048, 256, 0, stream>>>(encbf, bw, hx, vw, epart);
  } else {
    k_attn<<<2048, 256, 0, stream>>>(enc, bw, hx, vw, epart);
  }
  k_softmax<<<64, 256, 0, stream>>>(epart, score);
  k_ctx<<<1024, 256, 0, stream>>>(enc, score, cpart);
  k_ctxred<<<128, 256, 0, stream>>>(cpart, ctx);
  k_grugemm<<<384, 256, 0, stream>>>(ctx, wvbuf, hidden, Wih, bih, Whh, bhh, gi, gh);
  k_gate<<<256, 256, 0, stream>>>(gi, gh, hidden, newh);
  k_outproj<<<500, 256, 0, stream>>>(newh, ow, ob, pred);
}

// Round 3
// 607.492 us; speedup vs baseline: 1.0113x; 1.0113x over previous
//
#include <hip/hip_runtime.h>
#include <hip/hip_bf16.h>
#include <stdint.h>

typedef __attribute__((ext_vector_type(4))) float f32x4;
typedef __attribute__((ext_vector_type(8))) short short8;

#define B_   64
#define S_   512
#define H_   1024
#define E_   512
#define V_   32000
#define M_   2048            // D*H
#define BS_  32768           // B*S
#define XIN_ 2560            // M_+E_
#define G3_  3072

__device__ __forceinline__ unsigned short f2bf(float f) {
  union { float f; unsigned u; } x; x.f = f;
  unsigned r = x.u + 0x7fffu + ((x.u >> 16) & 1u);
  return (unsigned short)(r >> 16);
}

__device__ __forceinline__ float bf2f(unsigned short u) {
  union { unsigned u; float f; } x; x.u = (unsigned)u << 16; return x.f;
}

__device__ __forceinline__ void async16(const void* g, void* l) {
  __builtin_amdgcn_global_load_lds((const __attribute__((address_space(1))) unsigned*)g,
                                   (__attribute__((address_space(3))) unsigned*)l,
                                   16, 0, 0);
}

// ---------------- enc f32 -> bf16 (one-time, pure BW) ----------------
__global__ __launch_bounds__(256) void k_enc2bf(const float* __restrict__ enc,
                                                unsigned short* __restrict__ ebf) {
  const size_t n4 = (size_t)BS_ * M_ / 4;  // 16,777,216
  for (size_t i = (size_t)blockIdx.x * 256 + threadIdx.x; i < n4;
       i += (size_t)gridDim.x * 256) {
    f32x4 v = *(const f32x4*)(enc + i * 4);
    ushort4 o = { f2bf(v.x), f2bf(v.y), f2bf(v.z), f2bf(v.w) };
    *(ushort4*)(ebf + i * 4) = o;
  }
}

// ---------------- prep: lin2_w -> bf16, word embedding gather ----------------
__global__ __launch_bounds__(256) void k_prep(const float* __restrict__ lin2w,
                                              unsigned short* __restrict__ bw,
                                              const int* __restrict__ word,
                                              const float* __restrict__ emb,
                                              float* __restrict__ wv) {
  int idx = blockIdx.x * 256 + threadIdx.x;
  const int NC = (H_ * M_) / 4;  // 524288
  if (idx < NC) {
    f32x4 v = *(const f32x4*)(lin2w + (size_t)idx * 4);
    ushort4 o = { f2bf(v.x), f2bf(v.y), f2bf(v.z), f2bf(v.w) };
    *(ushort4*)(bw + (size_t)idx * 4) = o;
  } else {
    int i2 = idx - NC;
    if (i2 < (B_ * E_) / 4) {    // 8192
      int i0 = i2 * 4;
      int b = i0 >> 9;
      int c = i0 & 511;
      f32x4 v = *(const f32x4*)(emb + (size_t)word[b] * E_ + c);
      *(f32x4*)(wv + i0) = v;
    }
  }
}

// ---------------- h_x = hidden @ lin1_w.T + b1 + b2 (LDS-tiled 64x64) -------
__global__ __launch_bounds__(256) void k_hx(const float* __restrict__ hidden,
                                            const float* __restrict__ w1,
                                            const float* __restrict__ b1,
                                            const float* __restrict__ b2,
                                            float* __restrict__ hx) {
  __shared__ float hs[64][36];
  __shared__ float Ws[64][36];
  const int t = threadIdx.x;
  const int hbase = blockIdx.x * 64;     // 16 blocks
  const int hb = t & 15, bb = t >> 4;
  const int srow = t >> 2, sc0 = (t & 3) * 8;
  float acc[4][4] = {};
  for (int kc = 0; kc < H_; kc += 32) {
    *(f32x4*)&hs[srow][sc0]     = *(const f32x4*)(hidden + (size_t)srow * H_ + kc + sc0);
    *(f32x4*)&hs[srow][sc0 + 4] = *(const f32x4*)(hidden + (size_t)srow * H_ + kc + sc0 + 4);
    *(f32x4*)&Ws[srow][sc0]     = *(const f32x4*)(w1 + (size_t)(hbase + srow) * H_ + kc + sc0);
    *(f32x4*)&Ws[srow][sc0 + 4] = *(const f32x4*)(w1 + (size_t)(hbase + srow) * H_ + kc + sc0 + 4);
    __syncthreads();
#pragma unroll
    for (int kk = 0; kk < 32; ++kk) {
      float a[4], w4[4];
#pragma unroll
      for (int i = 0; i < 4; ++i) a[i] = hs[bb * 4 + i][kk];
#pragma unroll
      for (int j = 0; j < 4; ++j) w4[j] = Ws[hb + 16 * j][kk];
#pragma unroll
      for (int i = 0; i < 4; ++i)
#pragma unroll
        for (int j = 0; j < 4; ++j) acc[i][j] += a[i] * w4[j];
    }
    __syncthreads();
  }
#pragma unroll
  for (int i = 0; i < 4; ++i)
#pragma unroll
    for (int j = 0; j < 4; ++j) {
      int h = hbase + hb + 16 * j;
      hx[(size_t)(bb * 4 + i) * H_ + h] = acc[i][j] + b1[h] + b2[h];
    }
}

// ---------------- attention GEMM: 256x256 tile, 4-phase counted-vmcnt -------
// A = encbf [32768 x 2048], B^T = lin2w_bf16 [1024 x 2048]
// 8 waves (2M x 4N), BK=64, LDS 128KB (2 slots x 2 halves x 128x64 x A,B)
// LDS layout per half: [k32 2][ks 4][row 128][8 bf16] -> conflict-free b128
__global__ __launch_bounds__(512, 2) void k_attn8(const unsigned short* __restrict__ encbf,
                                                  const unsigned short* __restrict__ bw,
                                                  const float* __restrict__ hx,
                                                  const float* __restrict__ vw,
                                                  float* __restrict__ epart) {
  extern __shared__ char smem[];   // 131072 B: A at 0, B at 65536
  const int t = threadIdx.x;
  const int wid = t >> 6, l = t & 63;
  const int wm = wid >> 2, wn = wid & 3;
  const int l15 = l & 15, l4 = l >> 4;

  // XCD-aware swizzle: 512 wgs -> 64 contiguous per XCD
  const int orig = blockIdx.x;
  const int wg = (orig & 7) * 64 + (orig >> 3);
  const int bm = wg >> 2, bn = wg & 3;

  // staging source bases (per-thread): row = t&127, k-sub = (t>>7)*8
  const int srow = t & 127, sk = (t >> 7) * 8;
  const unsigned short* aBase = encbf + (size_t)(bm * 256 + srow) * M_ + sk;
  const unsigned short* bBase = bw + (size_t)(bn * 256 + srow) * M_ + sk;

  // LDS read base offsets (bytes)
  const int rdA = wm * 16384 + l4 * 2048 + l15 * 16;
  const int rdB = 65536 + (wn >> 1) * 16384 + l4 * 2048 + (wn & 1) * 1024 + l15 * 16;

  f32x4 acc[8][4] = {};

#define STAGE_A(u, h, j) async16(aBase + (size_t)(h) * 128 * M_ + (u) * 64 + (j) * 32, \
    smem + (((u) & 1) * 32768 + (h) * 16384 + (j) * 8192 + t * 16))
#define STAGE_B(u, h, j) async16(bBase + (size_t)(h) * 128 * M_ + (u) * 64 + (j) * 32, \
    smem + (65536 + ((u) & 1) * 32768 + (h) * 16384 + (j) * 8192 + t * 16))
#define FENCE asm volatile("" ::: "memory")
#define BAR   do { FENCE; __builtin_amdgcn_s_barrier(); FENCE; } while (0)

  // prologue: stage tiles 0 and 1, retire tile 0 (8 newest stay in flight)
  STAGE_A(0, 0, 0); STAGE_A(0, 0, 1); STAGE_A(0, 1, 0); STAGE_A(0, 1, 1);
  STAGE_B(0, 0, 0); STAGE_B(0, 0, 1); STAGE_B(0, 1, 0); STAGE_B(0, 1, 1);
  STAGE_A(1, 0, 0); STAGE_A(1, 0, 1); STAGE_A(1, 1, 0); STAGE_A(1, 1, 1);
  STAGE_B(1, 0, 0); STAGE_B(1, 0, 1); STAGE_B(1, 1, 0); STAGE_B(1, 1, 1);
  asm volatile("s_waitcnt vmcnt(8)" ::: "memory");
  BAR;

  short8 a[4][2], b0[2][2], b1[2][2];
  for (int tt = 0; tt < 32; ++tt) {
    const int sbase = (tt & 1) * 32768;
    // ---- phase 1: (rh0, ch0) ----
#pragma unroll
    for (int mi = 0; mi < 4; ++mi)
#pragma unroll
      for (int k = 0; k < 2; ++k)
        a[mi][k] = *(const short8*)(smem + sbase + rdA + k * 8192 + mi * 256);
#pragma unroll
    for (int ni = 0; ni < 2; ++ni)
#pragma unroll
      for (int k = 0; k < 2; ++k)
        b0[ni][k] = *(const short8*)(smem + sbase + rdB + k * 8192 + ni * 256);
    BAR;
    __builtin_amdgcn_s_setprio(1);
#pragma unroll
    for (int mi = 0; mi < 4; ++mi)
#pragma unroll
      for (int ni = 0; ni < 2; ++ni)
#pragma unroll
        for (int k = 0; k < 2; ++k)
          acc[mi][ni] = __builtin_amdgcn_mfma_f32_16x16x32_bf16(a[mi][k], b0[ni][k], acc[mi][ni], 0, 0, 0);
    __builtin_amdgcn_s_setprio(0);
    BAR;
    // ---- phase 2: (rh0, ch1) ----
#pragma unroll
    for (int ni = 0; ni < 2; ++ni)
#pragma unroll
      for (int k = 0; k < 2; ++k)
        b1[ni][k] = *(const short8*)(smem + sbase + rdB + k * 8192 + 512 + ni * 256);
    BAR;
    __builtin_amdgcn_s_setprio(1);
#pragma unroll
    for (int mi = 0; mi < 4; ++mi)
#pragma unroll
      for (int ni = 0; ni < 2; ++ni)
#pragma unroll
        for (int k = 0; k < 2; ++k)
          acc[mi][2 + ni] = __builtin_amdgcn_mfma_f32_16x16x32_bf16(a[mi][k], b1[ni][k], acc[mi][2 + ni], 0, 0, 0);
    __builtin_amdgcn_s_setprio(0);
    BAR;
    // ---- phase 3: (rh1, ch1); stage B(t+2) half0 ----
#pragma unroll
    for (int mi = 0; mi < 4; ++mi)
#pragma unroll
      for (int k = 0; k < 2; ++k)
        a[mi][k] = *(const short8*)(smem + sbase + rdA + k * 8192 + 1024 + mi * 256);
    if (tt < 30) { STAGE_B(tt + 2, 0, 0); STAGE_B(tt + 2, 0, 1); }
    BAR;
    __builtin_amdgcn_s_setprio(1);
#pragma unroll
    for (int mi = 0; mi < 4; ++mi)
#pragma unroll
      for (int ni = 0; ni < 2; ++ni)
#pragma unroll
        for (int k = 0; k < 2; ++k)
          acc[4 + mi][2 + ni] = __builtin_amdgcn_mfma_f32_16x16x32_bf16(a[mi][k], b1[ni][k], acc[4 + mi][2 + ni], 0, 0, 0);
    __builtin_amdgcn_s_setprio(0);
    BAR;
    // ---- phase 4: (rh1, ch0); stage B(t+2) half1 + A(t+2) both halves ----
    if (tt < 30) {
      STAGE_B(tt + 2, 1, 0); STAGE_B(tt + 2, 1, 1);
      STAGE_A(tt + 2, 0, 0); STAGE_A(tt + 2, 0, 1);
      STAGE_A(tt + 2, 1, 0); STAGE_A(tt + 2, 1, 1);
      asm volatile("s_waitcnt vmcnt(8)" ::: "memory");  // retire tile t+1
    } else if (tt == 30) {
      asm volatile("s_waitcnt vmcnt(0)" ::: "memory");  // retire tile 31
    }
    BAR;
    __builtin_amdgcn_s_setprio(1);
#pragma unroll
    for (int mi = 0; mi < 4; ++mi)
#pragma unroll
      for (int ni = 0; ni < 2; ++ni)
#pragma unroll
        for (int k = 0; k < 2; ++k)
          acc[4 + mi][ni] = __builtin_amdgcn_mfma_f32_16x16x32_bf16(a[mi][k], b0[ni][k], acc[4 + mi][ni], 0, 0, 0);
    __builtin_amdgcn_s_setprio(0);
    BAR;
  }
#undef STAGE_A
#undef STAGE_B

  // epilogue: e-partial = sum over this wave's 64 cols of v*tanh(hx + C)
  const int b = bm >> 1;                  // 256-row tile aligned inside 512-row batch
  const int rbase = bm * 256 + wm * 128;
  const int cbase = bn * 256 + wn * 64;
  const int part = bn * 4 + wn;
#pragma unroll
  for (int rf = 0; rf < 8; ++rf) {
#pragma unroll
    for (int j = 0; j < 4; ++j) {
      int row = rbase + rf * 16 + l4 * 4 + j;
      float sum = 0.f;
#pragma unroll
      for (int cf = 0; cf < 4; ++cf) {
        int h = cbase + cf * 16 + l15;
        sum += vw[h] * tanhf(hx[b * H_ + h] + acc[rf][cf][j]);
      }
      sum += __shfl_xor(sum, 1);
      sum += __shfl_xor(sum, 2);
      sum += __shfl_xor(sum, 4);
      sum += __shfl_xor(sum, 8);
      if (l15 == 0) epart[(size_t)part * BS_ + row] = sum;
    }
  }
}

// ---------------- attention GEMM (m97-style fallback, both bf16) ------------
__global__ __launch_bounds__(256) void k_attn_bf(const unsigned short* __restrict__ encbf,
                                                 const unsigned short* __restrict__ bw,
                                                 const float* __restrict__ hx,
                                                 const float* __restrict__ vw,
                                                 float* __restrict__ epart) {
  __shared__ unsigned short As[128 * 32];
  __shared__ unsigned short Bs[128 * 32];
  const int bid = blockIdx.x;
  const int bm = bid & 255, bn = bid >> 8;
  const int t = threadIdx.x;
  const int l = t & 63, w = t >> 6;
  const int wr = w >> 1, wc = w & 1;
  const int l15 = l & 15, l4 = l >> 4;

  f32x4 acc[4][4] = {};

  const unsigned short* Ag = encbf + (size_t)(bm * 128) * M_;
  const unsigned short* Bg = bw + (size_t)(bn * 128) * M_;

  const int sr = t >> 2;
  const int sc = (t & 3) * 8;

  for (int kt = 0; kt < 64; ++kt) {
    const int k0 = kt * 32;
    async16(Ag + (size_t)sr * M_ + k0 + sc, (char*)As + (size_t)t * 16);
    async16(Ag + (size_t)(sr + 64) * M_ + k0 + sc, (char*)As + 4096 + (size_t)t * 16);
    async16(Bg + (size_t)sr * M_ + k0 + sc, (char*)Bs + (size_t)t * 16);
    async16(Bg + (size_t)(sr + 64) * M_ + k0 + sc, (char*)Bs + 4096 + (size_t)t * 16);
    __syncthreads();
    short8 af[4], bf[4];
#pragma unroll
    for (int m = 0; m < 4; ++m)
      af[m] = *(const short8*)(As + (wr * 64 + m * 16 + l15) * 32 + l4 * 8);
#pragma unroll
    for (int n = 0; n < 4; ++n)
      bf[n] = *(const short8*)(Bs + (wc * 64 + n * 16 + l15) * 32 + l4 * 8);
#pragma unroll
    for (int m = 0; m < 4; ++m)
#pragma unroll
      for (int n = 0; n < 4; ++n)
        acc[m][n] = __builtin_amdgcn_mfma_f32_16x16x32_bf16(af[m], bf[n], acc[m][n], 0, 0, 0);
    __syncthreads();
  }

  const int colbase = bn * 128 + wc * 64;
#pragma unroll
  for (int m = 0; m < 4; ++m) {
#pragma unroll
    for (int j = 0; j < 4; ++j) {
      int rloc = wr * 64 + m * 16 + l4 * 4 + j;
      int rg = bm * 128 + rloc;
      int b = rg >> 9;
      float sum = 0.f;
#pragma unroll
      for (int n = 0; n < 4; ++n) {
        int h = colbase + n * 16 + l15;
        sum += vw[h] * tanhf(hx[b * H_ + h] + acc[m][n][j]);
      }
      sum += __shfl_xor(sum, 1);
      sum += __shfl_xor(sum, 2);
      sum += __shfl_xor(sum, 4);
      sum += __shfl_xor(sum, 8);
      if (l15 == 0) epart[(size_t)(bn * 2 + wc) * BS_ + rg] = sum;
    }
  }
}

// ---------------- attention GEMM (slow fallback: fused f32 A conversion) ----
__global__ __launch_bounds__(256) void k_attn(const float* __restrict__ enc,
                                              const unsigned short* __restrict__ bw,
                                              const float* __restrict__ hx,
                                              const float* __restrict__ vw,
                                              float* __restrict__ epart) {
  __shared__ unsigned short As[128 * 32];
  __shared__ unsigned short Bs[128 * 32];
  const int bid = blockIdx.x;
  const int bm = bid & 255, bn = bid >> 8;
  const int t = threadIdx.x;
  const int l = t & 63, w = t >> 6;
  const int wr = w >> 1, wc = w & 1;
  const int l15 = l & 15, l4 = l >> 4;

  f32x4 acc[4][4] = {};

  const float* Ag = enc + (size_t)(bm * 128) * M_;
  const unsigned short* Bg = bw + (size_t)(bn * 128) * M_;

  const int ar = t >> 3;
  const int ac = (t & 7) * 4;
  const int br = t >> 2;
  const int bc = (t & 3) * 8;

  for (int kt = 0; kt < 64; ++kt) {
    const int k0 = kt * 32;
    async16(Bg + (size_t)br * M_ + k0 + bc, (char*)Bs + (size_t)t * 16);
    async16(Bg + (size_t)(br + 64) * M_ + k0 + bc, (char*)Bs + 4096 + (size_t)t * 16);
#pragma unroll
    for (int j = 0; j < 4; ++j) {
      f32x4 v = *(const f32x4*)(Ag + (size_t)(ar + j * 32) * M_ + k0 + ac);
      ushort4 o = { f2bf(v.x), f2bf(v.y), f2bf(v.z), f2bf(v.w) };
      *(ushort4*)(As + (ar + j * 32) * 32 + ac) = o;
    }
    __syncthreads();
    short8 af[4], bf[4];
#pragma unroll
    for (int m = 0; m < 4; ++m)
      af[m] = *(const short8*)(As + (wr * 64 + m * 16 + l15) * 32 + l4 * 8);
#pragma unroll
    for (int n = 0; n < 4; ++n)
      bf[n] = *(const short8*)(Bs + (wc * 64 + n * 16 + l15) * 32 + l4 * 8);
#pragma unroll
    for (int m = 0; m < 4; ++m)
#pragma unroll
      for (int n = 0; n < 4; ++n)
        acc[m][n] = __builtin_amdgcn_mfma_f32_16x16x32_bf16(af[m], bf[n], acc[m][n], 0, 0, 0);
    __syncthreads();
  }

  const int colbase = bn * 128 + wc * 64;
#pragma unroll
  for (int m = 0; m < 4; ++m) {
#pragma unroll
    for (int j = 0; j < 4; ++j) {
      int rloc = wr * 64 + m * 16 + l4 * 4 + j;
      int rg = bm * 128 + rloc;
      int b = rg >> 9;
      float sum = 0.f;
#pragma unroll
      for (int n = 0; n < 4; ++n) {
        int h = colbase + n * 16 + l15;
        sum += vw[h] * tanhf(hx[b * H_ + h] + acc[m][n][j]);
      }
      sum += __shfl_xor(sum, 1);
      sum += __shfl_xor(sum, 2);
      sum += __shfl_xor(sum, 4);
      sum += __shfl_xor(sum, 8);
      if (l15 == 0) epart[(size_t)(bn * 2 + wc) * BS_ + rg] = sum;
    }
  }
}

// ---------------- softmax over S per batch row (reduces 16 e-partials) ------
__global__ __launch_bounds__(256) void k_softmax(const float* __restrict__ epart,
                                                 float* __restrict__ score) {
  int b = blockIdx.x, t = threadIdx.x;
  float v0 = 0.f, v1 = 0.f;
#pragma unroll
  for (int p = 0; p < 16; ++p) {
    v0 += epart[(size_t)p * BS_ + b * S_ + t];
    v1 += epart[(size_t)p * BS_ + b * S_ + 256 + t];
  }
  int w = t >> 6, l = t & 63;
  float m = fmaxf(v0, v1);
#pragma unroll
  for (int off = 32; off; off >>= 1) m = fmaxf(m, __shfl_xor(m, off));
  __shared__ float sm[4];
  __shared__ float ssum[4];
  if (l == 0) sm[w] = m;
  __syncthreads();
  float M = fmaxf(fmaxf(sm[0], sm[1]), fmaxf(sm[2], sm[3]));
  float p0 = expf(v0 - M), p1 = expf(v1 - M);
  float s = p0 + p1;
#pragma unroll
  for (int off = 32; off; off >>= 1) s += __shfl_xor(s, off);
  if (l == 0) ssum[w] = s;
  __syncthreads();
  float inv = 1.f / (ssum[0] + ssum[1] + ssum[2] + ssum[3]);
  score[b * S_ + t] = p0 * inv;
  score[b * S_ + 256 + t] = p1 * inv;
}

// ---------------- context partials (bf16 enc read) ----------------
__global__ __launch_bounds__(256) void k_ctxb(const unsigned short* __restrict__ encbf,
                                              const float* __restrict__ score,
                                              float* __restrict__ cpart) {
  int blk = blockIdx.x;            // 512 = b(64) x sc(8)
  int b = blk >> 3, sc = blk & 7;
  int t = threadIdx.x;
  int m = t * 8;
  f32x4 acc0 = {0.f, 0.f, 0.f, 0.f}, acc1 = {0.f, 0.f, 0.f, 0.f};
  const unsigned short* ep = encbf + (size_t)(b * S_ + sc * 64) * M_ + m;
  const float* sp = score + b * S_ + sc * 64;
#pragma unroll 4
  for (int s8 = 0; s8 < 64; ++s8) {
    float sv = sp[s8];
    short8 v = *(const short8*)(ep + (size_t)s8 * M_);
    acc0.x += bf2f((unsigned short)v[0]) * sv;
    acc0.y += bf2f((unsigned short)v[1]) * sv;
    acc0.z += bf2f((unsigned short)v[2]) * sv;
    acc0.w += bf2f((unsigned short)v[3]) * sv;
    acc1.x += bf2f((unsigned short)v[4]) * sv;
    acc1.y += bf2f((unsigned short)v[5]) * sv;
    acc1.z += bf2f((unsigned short)v[6]) * sv;
    acc1.w += bf2f((unsigned short)v[7]) * sv;
  }
  float* dst = cpart + (size_t)sc * (B_ * M_) + b * M_ + m;
  *(f32x4*)dst = acc0;
  *(f32x4*)(dst + 4) = acc1;
}

// ---------------- context partials (f32 fallback) ----------------
__global__ __launch_bounds__(256) void k_ctx(const float* __restrict__ enc,
                                             const float* __restrict__ score,
                                             float* __restrict__ cpart) {
  int blk = blockIdx.x;
  int b = blk >> 4, mc = (blk >> 3) & 1, sc = blk & 7;
  int t = threadIdx.x;
  int m = mc * 1024 + t * 4;
  f32x4 acc = {0.f, 0.f, 0.f, 0.f};
  const float* ep = enc + (size_t)b * S_ * M_ + m;
  const float* sp = score + b * S_ + sc * 64;
#pragma unroll 4
  for (int s8 = 0; s8 < 64; ++s8) {
    float sv = sp[s8];
    f32x4 v = *(const f32x4*)(ep + (size_t)(sc * 64 + s8) * M_);
    acc += v * sv;
  }
  *(f32x4*)(cpart + (size_t)sc * (B_ * M_) + b * M_ + m) = acc;
}

__global__ void k_ctxred(const float* __restrict__ cpart, float* __restrict__ ctx) {
  int i0 = (blockIdx.x * 256 + threadIdx.x) * 4;
  f32x4 a = {0.f, 0.f, 0.f, 0.f};
#pragma unroll
  for (int p = 0; p < 8; ++p) a += *(const f32x4*)(cpart + (size_t)p * (B_ * M_) + i0);
  *(f32x4*)(ctx + i0) = a;
}

// ---------------- GRU input/hidden GEMMs ----------------
__global__ __launch_bounds__(256) void k_grugemm(const float* __restrict__ ctx,
                                                 const float* __restrict__ wv,
                                                 const float* __restrict__ hidden,
                                                 const float* __restrict__ Wih,
                                                 const float* __restrict__ bih,
                                                 const float* __restrict__ Whh,
                                                 const float* __restrict__ bhh,
                                                 float* __restrict__ gi,
                                                 float* __restrict__ gh) {
  __shared__ float xs[64][36];
  __shared__ float Ws[16][36];
  const int t = threadIdx.x;
  const bool ghh = blockIdx.x >= 192;
  const int gbase = (ghh ? blockIdx.x - 192 : blockIdx.x) * 16;
  const int K = ghh ? H_ : XIN_;
  const float* Wp = ghh ? Whh : Wih;
  float acc[4] = {0.f, 0.f, 0.f, 0.f};
  const int g = t & 15, bb = t >> 4;
  const int srow = t >> 2, sc0 = (t & 3) * 8;
  const int wrow = t >> 3, wc0 = (t & 7) * 4;
  for (int kc = 0; kc < K; kc += 32) {
    f32x4 xa, xb;
    if (ghh) {
      xa = *(const f32x4*)(hidden + (size_t)srow * H_ + kc + sc0);
      xb = *(const f32x4*)(hidden + (size_t)srow * H_ + kc + sc0 + 4);
    } else if (kc + sc0 < M_) {
      xa = *(const f32x4*)(ctx + (size_t)srow * M_ + kc + sc0);
      xb = *(const f32x4*)(ctx + (size_t)srow * M_ + kc + sc0 + 4);
    } else {
      xa = *(const f32x4*)(wv + (size_t)srow * E_ + kc + sc0 - M_);
      xb = *(const f32x4*)(wv + (size_t)srow * E_ + kc + sc0 - M_ + 4);
    }
    *(f32x4*)&xs[srow][sc0] = xa;
    *(f32x4*)&xs[srow][sc0 + 4] = xb;
    if (t < 128) {
      f32x4 w4 = *(const f32x4*)(Wp + (size_t)(gbase + wrow) * K + kc + wc0);
      *(f32x4*)&Ws[wrow][wc0] = w4;
    }
    __syncthreads();
#pragma unroll
    for (int kk = 0; kk < 32; ++kk) {
      float wgt = Ws[g][kk];
#pragma unroll
      for (int i = 0; i < 4; ++i) acc[i] += xs[bb * 4 + i][kk] * wgt;
    }
    __syncthreads();
  }
  float* dst = ghh ? gh : gi;
  const float* bias = ghh ? bhh : bih;
#pragma unroll
  for (int i = 0; i < 4; ++i)
    dst[(size_t)(bb * 4 + i) * G3_ + gbase + g] = acc[i] + bias[gbase + g];
}

// ---------------- GRU gates -> new_hidden ----------------
__global__ void k_gate(const float* __restrict__ gi, const float* __restrict__ gh,
                       const float* __restrict__ hidden, float* __restrict__ newh) {
  int o = blockIdx.x * 256 + threadIdx.x;
  int b = o >> 10, h = o & 1023;
  const float* gib = gi + (size_t)b * G3_;
  const float* ghb = gh + (size_t)b * G3_;
  float r = 1.f / (1.f + expf(-(gib[h] + ghb[h])));
  float z = 1.f / (1.f + expf(-(gib[1024 + h] + ghb[1024 + h])));
  float n = tanhf(gib[2048 + h] + r * ghb[2048 + h]);
  newh[o] = (1.f - z) * n + z * hidden[o];
}

// ---------------- output projection ----------------
__global__ __launch_bounds__(256) void k_outproj(const float* __restrict__ newh,
                                                 const float* __restrict__ ow,
                                                 const float* __restrict__ ob,
                                                 float* __restrict__ pred) {
  __shared__ float hs[64][36];
  __shared__ float Ws[64][36];
  const int t = threadIdx.x;
  const int vbase = blockIdx.x * 64;
  const int vb = t & 15, bb = t >> 4;
  const int srow = t >> 2, sc0 = (t & 3) * 8;
  float acc[4][4] = {};
  for (int kc = 0; kc < H_; kc += 32) {
    *(f32x4*)&hs[srow][sc0]     = *(const f32x4*)(newh + (size_t)srow * H_ + kc + sc0);
    *(f32x4*)&hs[srow][sc0 + 4] = *(const f32x4*)(newh + (size_t)srow * H_ + kc + sc0 + 4);
    *(f32x4*)&Ws[srow][sc0]     = *(const f32x4*)(ow + (size_t)(vbase + srow) * H_ + kc + sc0);
    *(f32x4*)&Ws[srow][sc0 + 4] = *(const f32x4*)(ow + (size_t)(vbase + srow) * H_ + kc + sc0 + 4);
    __syncthreads();
#pragma unroll
    for (int kk = 0; kk < 32; ++kk) {
      float a[4], w4[4];
#pragma unroll
      for (int i = 0; i < 4; ++i) a[i] = hs[bb * 4 + i][kk];
#pragma unroll
      for (int j = 0; j < 4; ++j) w4[j] = Ws[vb + 16 * j][kk];
#pragma unroll
      for (int i = 0; i < 4; ++i)
#pragma unroll
        for (int j = 0; j < 4; ++j) acc[i][j] += a[i] * w4[j];
    }
    __syncthreads();
  }
#pragma unroll
  for (int i = 0; i < 4; ++i)
#pragma unroll
    for (int j = 0; j < 4; ++j)
      pred[(size_t)(bb * 4 + i) * V_ + vbase + vb + 16 * j] = acc[i][j] + ob[vbase + vb + 16 * j];
}

extern "C" void kernel_launch(void* const* d_in, const int* in_sizes, int n_in,
                              void* d_out, int out_size, void* d_ws, size_t ws_size,
                              hipStream_t stream) {
  const int*   word   = (const int*)d_in[0];
  const float* hidden = (const float*)d_in[1];
  const float* enc    = (const float*)d_in[2];
  const float* emb    = (const float*)d_in[5];
  const float* lin1w  = (const float*)d_in[6];
  const float* lin1b  = (const float*)d_in[7];
  const float* lin2w  = (const float*)d_in[8];
  const float* lin2b  = (const float*)d_in[9];
  const float* vw     = (const float*)d_in[10];
  const float* Wih    = (const float*)d_in[12];
  const float* bih    = (const float*)d_in[13];
  const float* Whh    = (const float*)d_in[14];
  const float* bhh    = (const float*)d_in[15];
  const float* ow     = (const float*)d_in[16];
  const float* ob     = (const float*)d_in[17];

  float* out   = (float*)d_out;
  float* pred  = out;                   // [64][32000]
  float* newh  = out + 2048000;         // [64][1024]
  float* score = out + 2113536;         // [64][512]

  const size_t ENCBF = 134217728;       // 32768*2048*2
  const bool fast = ws_size >= ENCBF + 12976128;
  char* ws = (char*)d_ws;
  unsigned short* encbf = (unsigned short*)ws;      // fast path only
  size_t base = fast ? ENCBF : 0;
  unsigned short* bw = (unsigned short*)(ws + base);        // 4,194,304
  float* hx    = (float*)(ws + base + 4194304);             // 262,144
  float* wvbuf = (float*)(ws + base + 4456448);             // 131,072
  float* epart = (float*)(ws + base + 4587520);             // 2,097,152
  float* cpart = (float*)(ws + base + 6684672);             // 4,194,304
  float* ctx   = (float*)(ws + base + 10878976);            // 524,288
  float* gi    = (float*)(ws + base + 11403264);            // 786,432
  float* gh    = (float*)(ws + base + 12189696);            // 786,432

  bool use8 = false;
  if (fast) {
    hipError_t e = hipFuncSetAttribute((const void*)k_attn8,
        hipFuncAttributeMaxDynamicSharedMemorySize, 131072);
    use8 = (e == hipSuccess);
  }

  k_prep<<<2080, 256, 0, stream>>>(lin2w, bw, word, emb, wvbuf);
  k_hx<<<16, 256, 0, stream>>>(hidden, lin1w, lin1b, lin2b, hx);
  if (fast) {
    k_enc2bf<<<2048, 256, 0, stream>>>(enc, encbf);
    if (use8) {
      k_attn8<<<512, 512, 131072, stream>>>(encbf, bw, hx, vw, epart);
    } else {
      k_attn_bf<<<2048, 256, 0, stream>>>(encbf, bw, hx, vw, epart);
    }
    k_softmax<<<64, 256, 0, stream>>>(epart, score);
    k_ctxb<<<512, 256, 0, stream>>>(encbf, score, cpart);
  } else {
    k_attn<<<2048, 256, 0, stream>>>(enc, bw, hx, vw, epart);
    k_softmax<<<64, 256, 0, stream>>>(epart, score);
    k_ctx<<<1024, 256, 0, stream>>>(enc, score, cpart);
  }
  k_ctxred<<<128, 256, 0, stream>>>(cpart, ctx);
  k_grugemm<<<384, 256, 0, stream>>>(ctx, wvbuf, hidden, Wih, bih, Whh, bhh, gi, gh);
  k_gate<<<256, 256, 0, stream>>>(gi, gh, hidden, newh);
  k_outproj<<<500, 256, 0, stream>>>(newh, ow, ob, pred);
}

// Round 4
// 585.050 us; speedup vs baseline: 1.0501x; 1.0384x over previous
//
#include <hip/hip_runtime.h>
#include <hip/hip_bf16.h>
#include <stdint.h>

typedef __attribute__((ext_vector_type(4))) float f32x4;
typedef __attribute__((ext_vector_type(8))) short short8;

#define B_   64
#define S_   512
#define H_   1024
#define E_   512
#define V_   32000
#define M_   2048            // D*H
#define BS_  32768           // B*S
#define XIN_ 2560            // M_+E_
#define G3_  3072

__device__ __forceinline__ unsigned short f2bf(float f) {
  union { float f; unsigned u; } x; x.f = f;
  unsigned r = x.u + 0x7fffu + ((x.u >> 16) & 1u);
  return (unsigned short)(r >> 16);
}

__device__ __forceinline__ float bf2f(unsigned short u) {
  union { unsigned u; float f; } x; x.u = (unsigned)u << 16; return x.f;
}

__device__ __forceinline__ void async16(const void* g, void* l) {
  __builtin_amdgcn_global_load_lds((const __attribute__((address_space(1))) unsigned*)g,
                                   (__attribute__((address_space(3))) unsigned*)l,
                                   16, 0, 0);
}

// ---------------- enc f32 -> bf16 (one-time, pure BW) ----------------
__global__ __launch_bounds__(256) void k_enc2bf(const float* __restrict__ enc,
                                                unsigned short* __restrict__ ebf) {
  const size_t n4 = (size_t)BS_ * M_ / 4;  // 16,777,216
  for (size_t i = (size_t)blockIdx.x * 256 + threadIdx.x; i < n4;
       i += (size_t)gridDim.x * 256) {
    f32x4 v = *(const f32x4*)(enc + i * 4);
    ushort4 o = { f2bf(v.x), f2bf(v.y), f2bf(v.z), f2bf(v.w) };
    *(ushort4*)(ebf + i * 4) = o;
  }
}

// ---------------- prep: lin2_w -> bf16, word embedding gather ----------------
__global__ __launch_bounds__(256) void k_prep(const float* __restrict__ lin2w,
                                              unsigned short* __restrict__ bw,
                                              const int* __restrict__ word,
                                              const float* __restrict__ emb,
                                              float* __restrict__ wv) {
  int idx = blockIdx.x * 256 + threadIdx.x;
  const int NC = (H_ * M_) / 4;  // 524288
  if (idx < NC) {
    f32x4 v = *(const f32x4*)(lin2w + (size_t)idx * 4);
    ushort4 o = { f2bf(v.x), f2bf(v.y), f2bf(v.z), f2bf(v.w) };
    *(ushort4*)(bw + (size_t)idx * 4) = o;
  } else {
    int i2 = idx - NC;
    if (i2 < (B_ * E_) / 4) {    // 8192
      int i0 = i2 * 4;
      int b = i0 >> 9;
      int c = i0 & 511;
      f32x4 v = *(const f32x4*)(emb + (size_t)word[b] * E_ + c);
      *(f32x4*)(wv + i0) = v;
    }
  }
}

// ---------------- h_x = hidden @ lin1_w.T + b1 + b2 (LDS-tiled 64x64) -------
__global__ __launch_bounds__(256) void k_hx(const float* __restrict__ hidden,
                                            const float* __restrict__ w1,
                                            const float* __restrict__ b1,
                                            const float* __restrict__ b2,
                                            float* __restrict__ hx) {
  __shared__ float hs[64][36];
  __shared__ float Ws[64][36];
  const int t = threadIdx.x;
  const int hbase = blockIdx.x * 64;     // 16 blocks
  const int hb = t & 15, bb = t >> 4;
  const int srow = t >> 2, sc0 = (t & 3) * 8;
  float acc[4][4] = {};
  for (int kc = 0; kc < H_; kc += 32) {
    *(f32x4*)&hs[srow][sc0]     = *(const f32x4*)(hidden + (size_t)srow * H_ + kc + sc0);
    *(f32x4*)&hs[srow][sc0 + 4] = *(const f32x4*)(hidden + (size_t)srow * H_ + kc + sc0 + 4);
    *(f32x4*)&Ws[srow][sc0]     = *(const f32x4*)(w1 + (size_t)(hbase + srow) * H_ + kc + sc0);
    *(f32x4*)&Ws[srow][sc0 + 4] = *(const f32x4*)(w1 + (size_t)(hbase + srow) * H_ + kc + sc0 + 4);
    __syncthreads();
#pragma unroll
    for (int kk = 0; kk < 32; ++kk) {
      float a[4], w4[4];
#pragma unroll
      for (int i = 0; i < 4; ++i) a[i] = hs[bb * 4 + i][kk];
#pragma unroll
      for (int j = 0; j < 4; ++j) w4[j] = Ws[hb + 16 * j][kk];
#pragma unroll
      for (int i = 0; i < 4; ++i)
#pragma unroll
        for (int j = 0; j < 4; ++j) acc[i][j] += a[i] * w4[j];
    }
    __syncthreads();
  }
#pragma unroll
  for (int i = 0; i < 4; ++i)
#pragma unroll
    for (int j = 0; j < 4; ++j) {
      int h = hbase + hb + 16 * j;
      hx[(size_t)(bb * 4 + i) * H_ + h] = acc[i][j] + b1[h] + b2[h];
    }
}

// ---------------- attention GEMM (m97 structure, both bf16) ------------------
// mapping: XCD-chunked, bn-inner so the 8 bn-blocks of one bm are adjacent
__global__ __launch_bounds__(256) void k_attn_bf(const unsigned short* __restrict__ encbf,
                                                 const unsigned short* __restrict__ bw,
                                                 const float* __restrict__ hx,
                                                 const float* __restrict__ vw,
                                                 float* __restrict__ epart) {
  __shared__ unsigned short As[128 * 32];
  __shared__ unsigned short Bs[128 * 32];
  const int bid = blockIdx.x;              // 2048
  const int xcd = bid & 7, idx = bid >> 3; // idx 0..255
  const int bm = xcd * 32 + (idx >> 3);    // XCD x owns bm x*32..x*32+31
  const int bn = idx & 7;                  // bn-inner: A-panel reused by 8 adj blocks
  const int t = threadIdx.x;
  const int l = t & 63, w = t >> 6;
  const int wr = w >> 1, wc = w & 1;
  const int l15 = l & 15, l4 = l >> 4;

  f32x4 acc[4][4] = {};

  const unsigned short* Ag = encbf + (size_t)(bm * 128) * M_;
  const unsigned short* Bg = bw + (size_t)(bn * 128) * M_;

  const int sr = t >> 2;
  const int sc = (t & 3) * 8;

  for (int kt = 0; kt < 64; ++kt) {
    const int k0 = kt * 32;
    async16(Ag + (size_t)sr * M_ + k0 + sc, (char*)As + (size_t)t * 16);
    async16(Ag + (size_t)(sr + 64) * M_ + k0 + sc, (char*)As + 4096 + (size_t)t * 16);
    async16(Bg + (size_t)sr * M_ + k0 + sc, (char*)Bs + (size_t)t * 16);
    async16(Bg + (size_t)(sr + 64) * M_ + k0 + sc, (char*)Bs + 4096 + (size_t)t * 16);
    __syncthreads();
    short8 af[4], bf[4];
#pragma unroll
    for (int m = 0; m < 4; ++m)
      af[m] = *(const short8*)(As + (wr * 64 + m * 16 + l15) * 32 + l4 * 8);
#pragma unroll
    for (int n = 0; n < 4; ++n)
      bf[n] = *(const short8*)(Bs + (wc * 64 + n * 16 + l15) * 32 + l4 * 8);
#pragma unroll
    for (int m = 0; m < 4; ++m)
#pragma unroll
      for (int n = 0; n < 4; ++n)
        acc[m][n] = __builtin_amdgcn_mfma_f32_16x16x32_bf16(af[m], bf[n], acc[m][n], 0, 0, 0);
    __syncthreads();
  }

  const int colbase = bn * 128 + wc * 64;
#pragma unroll
  for (int m = 0; m < 4; ++m) {
#pragma unroll
    for (int j = 0; j < 4; ++j) {
      int rloc = wr * 64 + m * 16 + l4 * 4 + j;
      int rg = bm * 128 + rloc;
      int b = rg >> 9;
      float sum = 0.f;
#pragma unroll
      for (int n = 0; n < 4; ++n) {
        int h = colbase + n * 16 + l15;
        sum += vw[h] * tanhf(hx[b * H_ + h] + acc[m][n][j]);
      }
      sum += __shfl_xor(sum, 1);
      sum += __shfl_xor(sum, 2);
      sum += __shfl_xor(sum, 4);
      sum += __shfl_xor(sum, 8);
      if (l15 == 0) epart[(size_t)(bn * 2 + wc) * BS_ + rg] = sum;
    }
  }
}

// ---------------- attention GEMM (slow fallback: fused f32 A conversion) ----
__global__ __launch_bounds__(256) void k_attn(const float* __restrict__ enc,
                                              const unsigned short* __restrict__ bw,
                                              const float* __restrict__ hx,
                                              const float* __restrict__ vw,
                                              float* __restrict__ epart) {
  __shared__ unsigned short As[128 * 32];
  __shared__ unsigned short Bs[128 * 32];
  const int bid = blockIdx.x;
  const int bm = bid & 255, bn = bid >> 8;
  const int t = threadIdx.x;
  const int l = t & 63, w = t >> 6;
  const int wr = w >> 1, wc = w & 1;
  const int l15 = l & 15, l4 = l >> 4;

  f32x4 acc[4][4] = {};

  const float* Ag = enc + (size_t)(bm * 128) * M_;
  const unsigned short* Bg = bw + (size_t)(bn * 128) * M_;

  const int ar = t >> 3;
  const int ac = (t & 7) * 4;
  const int br = t >> 2;
  const int bc = (t & 3) * 8;

  for (int kt = 0; kt < 64; ++kt) {
    const int k0 = kt * 32;
    async16(Bg + (size_t)br * M_ + k0 + bc, (char*)Bs + (size_t)t * 16);
    async16(Bg + (size_t)(br + 64) * M_ + k0 + bc, (char*)Bs + 4096 + (size_t)t * 16);
#pragma unroll
    for (int j = 0; j < 4; ++j) {
      f32x4 v = *(const f32x4*)(Ag + (size_t)(ar + j * 32) * M_ + k0 + ac);
      ushort4 o = { f2bf(v.x), f2bf(v.y), f2bf(v.z), f2bf(v.w) };
      *(ushort4*)(As + (ar + j * 32) * 32 + ac) = o;
    }
    __syncthreads();
    short8 af[4], bf[4];
#pragma unroll
    for (int m = 0; m < 4; ++m)
      af[m] = *(const short8*)(As + (wr * 64 + m * 16 + l15) * 32 + l4 * 8);
#pragma unroll
    for (int n = 0; n < 4; ++n)
      bf[n] = *(const short8*)(Bs + (wc * 64 + n * 16 + l15) * 32 + l4 * 8);
#pragma unroll
    for (int m = 0; m < 4; ++m)
#pragma unroll
      for (int n = 0; n < 4; ++n)
        acc[m][n] = __builtin_amdgcn_mfma_f32_16x16x32_bf16(af[m], bf[n], acc[m][n], 0, 0, 0);
    __syncthreads();
  }

  const int colbase = bn * 128 + wc * 64;
#pragma unroll
  for (int m = 0; m < 4; ++m) {
#pragma unroll
    for (int j = 0; j < 4; ++j) {
      int rloc = wr * 64 + m * 16 + l4 * 4 + j;
      int rg = bm * 128 + rloc;
      int b = rg >> 9;
      float sum = 0.f;
#pragma unroll
      for (int n = 0; n < 4; ++n) {
        int h = colbase + n * 16 + l15;
        sum += vw[h] * tanhf(hx[b * H_ + h] + acc[m][n][j]);
      }
      sum += __shfl_xor(sum, 1);
      sum += __shfl_xor(sum, 2);
      sum += __shfl_xor(sum, 4);
      sum += __shfl_xor(sum, 8);
      if (l15 == 0) epart[(size_t)(bn * 2 + wc) * BS_ + rg] = sum;
    }
  }
}

// ---------------- softmax over S per batch row (reduces 16 e-partials) ------
__global__ __launch_bounds__(256) void k_softmax(const float* __restrict__ epart,
                                                 float* __restrict__ score) {
  int b = blockIdx.x, t = threadIdx.x;
  float v0 = 0.f, v1 = 0.f;
#pragma unroll
  for (int p = 0; p < 16; ++p) {
    v0 += epart[(size_t)p * BS_ + b * S_ + t];
    v1 += epart[(size_t)p * BS_ + b * S_ + 256 + t];
  }
  int w = t >> 6, l = t & 63;
  float m = fmaxf(v0, v1);
#pragma unroll
  for (int off = 32; off; off >>= 1) m = fmaxf(m, __shfl_xor(m, off));
  __shared__ float sm[4];
  __shared__ float ssum[4];
  if (l == 0) sm[w] = m;
  __syncthreads();
  float M = fmaxf(fmaxf(sm[0], sm[1]), fmaxf(sm[2], sm[3]));
  float p0 = expf(v0 - M), p1 = expf(v1 - M);
  float s = p0 + p1;
#pragma unroll
  for (int off = 32; off; off >>= 1) s += __shfl_xor(s, off);
  if (l == 0) ssum[w] = s;
  __syncthreads();
  float inv = 1.f / (ssum[0] + ssum[1] + ssum[2] + ssum[3]);
  score[b * S_ + t] = p0 * inv;
  score[b * S_ + 256 + t] = p1 * inv;
}

// ---------------- context partials (bf16 enc read) ----------------
__global__ __launch_bounds__(256) void k_ctxb(const unsigned short* __restrict__ encbf,
                                              const float* __restrict__ score,
                                              float* __restrict__ cpart) {
  int blk = blockIdx.x;            // 512 = b(64) x sc(8)
  int b = blk >> 3, sc = blk & 7;
  int t = threadIdx.x;
  int m = t * 8;
  f32x4 acc0 = {0.f, 0.f, 0.f, 0.f}, acc1 = {0.f, 0.f, 0.f, 0.f};
  const unsigned short* ep = encbf + (size_t)(b * S_ + sc * 64) * M_ + m;
  const float* sp = score + b * S_ + sc * 64;
#pragma unroll 4
  for (int s8 = 0; s8 < 64; ++s8) {
    float sv = sp[s8];
    short8 v = *(const short8*)(ep + (size_t)s8 * M_);
    acc0.x += bf2f((unsigned short)v[0]) * sv;
    acc0.y += bf2f((unsigned short)v[1]) * sv;
    acc0.z += bf2f((unsigned short)v[2]) * sv;
    acc0.w += bf2f((unsigned short)v[3]) * sv;
    acc1.x += bf2f((unsigned short)v[4]) * sv;
    acc1.y += bf2f((unsigned short)v[5]) * sv;
    acc1.z += bf2f((unsigned short)v[6]) * sv;
    acc1.w += bf2f((unsigned short)v[7]) * sv;
  }
  float* dst = cpart + (size_t)sc * (B_ * M_) + b * M_ + m;
  *(f32x4*)dst = acc0;
  *(f32x4*)(dst + 4) = acc1;
}

// ---------------- context partials (f32 fallback) ----------------
__global__ __launch_bounds__(256) void k_ctx(const float* __restrict__ enc,
                                             const float* __restrict__ score,
                                             float* __restrict__ cpart) {
  int blk = blockIdx.x;
  int b = blk >> 4, mc = (blk >> 3) & 1, sc = blk & 7;
  int t = threadIdx.x;
  int m = mc * 1024 + t * 4;
  f32x4 acc = {0.f, 0.f, 0.f, 0.f};
  const float* ep = enc + (size_t)b * S_ * M_ + m;
  const float* sp = score + b * S_ + sc * 64;
#pragma unroll 4
  for (int s8 = 0; s8 < 64; ++s8) {
    float sv = sp[s8];
    f32x4 v = *(const f32x4*)(ep + (size_t)(sc * 64 + s8) * M_);
    acc += v * sv;
  }
  *(f32x4*)(cpart + (size_t)sc * (B_ * M_) + b * M_ + m) = acc;
}

__global__ void k_ctxred(const float* __restrict__ cpart, float* __restrict__ ctx) {
  int i0 = (blockIdx.x * 256 + threadIdx.x) * 4;
  f32x4 a = {0.f, 0.f, 0.f, 0.f};
#pragma unroll
  for (int p = 0; p < 8; ++p) a += *(const f32x4*)(cpart + (size_t)p * (B_ * M_) + i0);
  *(f32x4*)(ctx + i0) = a;
}

// ---------------- GRU GEMMs: 64x64 tile, 4x4 per thread ----------------
// blocks 0..47: gi = [ctx|wv] @ Wih.T (K=2560); 48..95: gh = hidden @ Whh.T (K=1024)
__global__ __launch_bounds__(256) void k_grugemm(const float* __restrict__ ctx,
                                                 const float* __restrict__ wv,
                                                 const float* __restrict__ hidden,
                                                 const float* __restrict__ Wih,
                                                 const float* __restrict__ bih,
                                                 const float* __restrict__ Whh,
                                                 const float* __restrict__ bhh,
                                                 float* __restrict__ gi,
                                                 float* __restrict__ gh) {
  __shared__ float xs[64][36];
  __shared__ float Ws[64][36];
  const int t = threadIdx.x;
  const bool ghh = blockIdx.x >= 48;
  const int gbase = (ghh ? blockIdx.x - 48 : blockIdx.x) * 64;
  const int K = ghh ? H_ : XIN_;
  const float* Wp = ghh ? Whh : Wih;
  const int vb = t & 15, bb = t >> 4;
  const int srow = t >> 2, sc0 = (t & 3) * 8;
  float acc[4][4] = {};
  for (int kc = 0; kc < K; kc += 32) {
    f32x4 xa, xb;
    if (ghh) {
      xa = *(const f32x4*)(hidden + (size_t)srow * H_ + kc + sc0);
      xb = *(const f32x4*)(hidden + (size_t)srow * H_ + kc + sc0 + 4);
    } else if (kc + sc0 < M_) {
      xa = *(const f32x4*)(ctx + (size_t)srow * M_ + kc + sc0);
      xb = *(const f32x4*)(ctx + (size_t)srow * M_ + kc + sc0 + 4);
    } else {
      xa = *(const f32x4*)(wv + (size_t)srow * E_ + kc + sc0 - M_);
      xb = *(const f32x4*)(wv + (size_t)srow * E_ + kc + sc0 - M_ + 4);
    }
    *(f32x4*)&xs[srow][sc0] = xa;
    *(f32x4*)&xs[srow][sc0 + 4] = xb;
    *(f32x4*)&Ws[srow][sc0]     = *(const f32x4*)(Wp + (size_t)(gbase + srow) * K + kc + sc0);
    *(f32x4*)&Ws[srow][sc0 + 4] = *(const f32x4*)(Wp + (size_t)(gbase + srow) * K + kc + sc0 + 4);
    __syncthreads();
#pragma unroll
    for (int kk = 0; kk < 32; ++kk) {
      float a[4], w4[4];
#pragma unroll
      for (int i = 0; i < 4; ++i) a[i] = xs[bb * 4 + i][kk];
#pragma unroll
      for (int j = 0; j < 4; ++j) w4[j] = Ws[vb + 16 * j][kk];
#pragma unroll
      for (int i = 0; i < 4; ++i)
#pragma unroll
        for (int j = 0; j < 4; ++j) acc[i][j] += a[i] * w4[j];
    }
    __syncthreads();
  }
  float* dst = ghh ? gh : gi;
  const float* bias = ghh ? bhh : bih;
#pragma unroll
  for (int i = 0; i < 4; ++i)
#pragma unroll
    for (int j = 0; j < 4; ++j) {
      int g = gbase + vb + 16 * j;
      dst[(size_t)(bb * 4 + i) * G3_ + g] = acc[i][j] + bias[g];
    }
}

// ---------------- GRU gates -> new_hidden (f32 + bf16 copy) ----------------
__global__ void k_gate(const float* __restrict__ gi, const float* __restrict__ gh,
                       const float* __restrict__ hidden, float* __restrict__ newh,
                       unsigned short* __restrict__ newhbf) {
  int o = blockIdx.x * 256 + threadIdx.x;
  int b = o >> 10, h = o & 1023;
  const float* gib = gi + (size_t)b * G3_;
  const float* ghb = gh + (size_t)b * G3_;
  float r = 1.f / (1.f + expf(-(gib[h] + ghb[h])));
  float z = 1.f / (1.f + expf(-(gib[1024 + h] + ghb[1024 + h])));
  float n = tanhf(gib[2048 + h] + r * ghb[2048 + h]);
  float nh = (1.f - z) * n + z * hidden[o];
  newh[o] = nh;
  newhbf[o] = f2bf(nh);
}

// ---------------- output projection: bf16 MFMA, 64x128 tile ----------------
// A = newhbf [64 x 1024]; B = ow [32000 x 1024] f32 converted during staging.
// LDS k-major (conflict-free): As[k16 4][row 64][8], Bs[k16 4][row 128][8]
__global__ __launch_bounds__(256) void k_outproj_mfma(const unsigned short* __restrict__ newhbf,
                                                      const float* __restrict__ ow,
                                                      const float* __restrict__ ob,
                                                      float* __restrict__ pred) {
  __shared__ unsigned short As[2048];   // 4 KB
  __shared__ unsigned short Bs[4096];   // 8 KB
  const int t = threadIdx.x;
  const int w = t >> 6, l = t & 63;
  const int l15 = l & 15, l4 = l >> 4;
  const int vbase = blockIdx.x * 128;   // 250 blocks

  // A stage: one async16/thread. LDS addr t*16 -> [k16=t>>6][row=t&63][8]
  const unsigned short* aSrc = newhbf + (size_t)(t & 63) * H_ + (t >> 6) * 8;
  // B stage: row r=t>>1, k-half (t&1)*16 -> k-groups kg0=(t&1)*2, kg0+1
  const int br = t >> 1, bh = t & 1;
  const float* bSrc = ow + (size_t)(vbase + br) * H_ + bh * 16;

  f32x4 acc[4][2] = {};

  for (int kc = 0; kc < H_; kc += 32) {
    async16(aSrc + kc, (char*)As + (size_t)t * 16);
    f32x4 v0 = *(const f32x4*)(bSrc + kc);
    f32x4 v1 = *(const f32x4*)(bSrc + kc + 4);
    f32x4 v2 = *(const f32x4*)(bSrc + kc + 8);
    f32x4 v3 = *(const f32x4*)(bSrc + kc + 12);
    ushort4 p0 = { f2bf(v0.x), f2bf(v0.y), f2bf(v0.z), f2bf(v0.w) };
    ushort4 p1 = { f2bf(v1.x), f2bf(v1.y), f2bf(v1.z), f2bf(v1.w) };
    ushort4 p2 = { f2bf(v2.x), f2bf(v2.y), f2bf(v2.z), f2bf(v2.w) };
    ushort4 p3 = { f2bf(v3.x), f2bf(v3.y), f2bf(v3.z), f2bf(v3.w) };
    const int kg0 = bh * 2;
    *(ushort4*)(Bs + kg0 * 1024 + br * 8)       = p0;
    *(ushort4*)(Bs + kg0 * 1024 + br * 8 + 4)   = p1;
    *(ushort4*)(Bs + (kg0 + 1) * 1024 + br * 8)     = p2;
    *(ushort4*)(Bs + (kg0 + 1) * 1024 + br * 8 + 4) = p3;
    __syncthreads();
    short8 af[4], bf[2];
#pragma unroll
    for (int rf = 0; rf < 4; ++rf)
      af[rf] = *(const short8*)(As + l4 * 512 + (rf * 16 + l15) * 8);
#pragma unroll
    for (int cf = 0; cf < 2; ++cf)
      bf[cf] = *(const short8*)(Bs + l4 * 1024 + (w * 32 + cf * 16 + l15) * 8);
#pragma unroll
    for (int rf = 0; rf < 4; ++rf)
#pragma unroll
      for (int cf = 0; cf < 2; ++cf)
        acc[rf][cf] = __builtin_amdgcn_mfma_f32_16x16x32_bf16(af[rf], bf[cf], acc[rf][cf], 0, 0, 0);
    __syncthreads();
  }

#pragma unroll
  for (int cf = 0; cf < 2; ++cf) {
    int col = vbase + w * 32 + cf * 16 + l15;
    float bias = ob[col];
#pragma unroll
    for (int rf = 0; rf < 4; ++rf)
#pragma unroll
      for (int j = 0; j < 4; ++j) {
        int row = rf * 16 + l4 * 4 + j;
        pred[(size_t)row * V_ + col] = acc[rf][cf][j] + bias;
      }
  }
}

extern "C" void kernel_launch(void* const* d_in, const int* in_sizes, int n_in,
                              void* d_out, int out_size, void* d_ws, size_t ws_size,
                              hipStream_t stream) {
  const int*   word   = (const int*)d_in[0];
  const float* hidden = (const float*)d_in[1];
  const float* enc    = (const float*)d_in[2];
  const float* emb    = (const float*)d_in[5];
  const float* lin1w  = (const float*)d_in[6];
  const float* lin1b  = (const float*)d_in[7];
  const float* lin2w  = (const float*)d_in[8];
  const float* lin2b  = (const float*)d_in[9];
  const float* vw     = (const float*)d_in[10];
  const float* Wih    = (const float*)d_in[12];
  const float* bih    = (const float*)d_in[13];
  const float* Whh    = (const float*)d_in[14];
  const float* bhh    = (const float*)d_in[15];
  const float* ow     = (const float*)d_in[16];
  const float* ob     = (const float*)d_in[17];

  float* out   = (float*)d_out;
  float* pred  = out;                   // [64][32000]
  float* newh  = out + 2048000;         // [64][1024]
  float* score = out + 2113536;         // [64][512]

  const size_t ENCBF = 134217728;       // 32768*2048*2
  const bool fast = ws_size >= ENCBF + 13238272;
  char* ws = (char*)d_ws;
  unsigned short* encbf = (unsigned short*)ws;      // fast path only
  size_t base = fast ? ENCBF : 0;
  unsigned short* bw = (unsigned short*)(ws + base);        // 4,194,304
  float* hx    = (float*)(ws + base + 4194304);             // 262,144
  float* wvbuf = (float*)(ws + base + 4456448);             // 131,072
  float* epart = (float*)(ws + base + 4587520);             // 2,097,152
  float* cpart = (float*)(ws + base + 6684672);             // 4,194,304
  float* ctx   = (float*)(ws + base + 10878976);            // 524,288
  float* gi    = (float*)(ws + base + 11403264);            // 786,432
  float* gh    = (float*)(ws + base + 12189696);            // 786,432
  unsigned short* nhbf = (unsigned short*)(ws + base + 12976128);  // 131,072

  k_prep<<<2080, 256, 0, stream>>>(lin2w, bw, word, emb, wvbuf);
  k_hx<<<16, 256, 0, stream>>>(hidden, lin1w, lin1b, lin2b, hx);
  if (fast) {
    k_enc2bf<<<2048, 256, 0, stream>>>(enc, encbf);
    k_attn_bf<<<2048, 256, 0, stream>>>(encbf, bw, hx, vw, epart);
    k_softmax<<<64, 256, 0, stream>>>(epart, score);
    k_ctxb<<<512, 256, 0, stream>>>(encbf, score, cpart);
  } else {
    k_attn<<<2048, 256, 0, stream>>>(enc, bw, hx, vw, epart);
    k_softmax<<<64, 256, 0, stream>>>(epart, score);
    k_ctx<<<1024, 256, 0, stream>>>(enc, score, cpart);
  }
  k_ctxred<<<128, 256, 0, stream>>>(cpart, ctx);
  k_grugemm<<<96, 256, 0, stream>>>(ctx, wvbuf, hidden, Wih, bih, Whh, bhh, gi, gh);
  k_gate<<<256, 256, 0, stream>>>(gi, gh, hidden, newh, nhbf);
  k_outproj_mfma<<<250, 256, 0, stream>>>(nhbf, ow, ob, pred);
}